// Round 1
// baseline (168.907 us; speedup 1.0000x reference)
//
#include <hip/hip_runtime.h>
#include <math.h>

// Problem constants (fixed by the reference)
constexpr int M_ROWS    = 16384;
constexpr int N_PTS     = 16384;
constexpr int MAX_EDGES = 4194304;
constexpr int TPB       = 256;
constexpr int NCHUNK    = 16;
constexpr int CHUNK     = N_PTS / NCHUNK;     // 1024
constexpr int ROWBLOCKS = M_ROWS / TPB;       // 64

// Pack [N,3] float -> float4 {x,y,z, (x*x+y*y)+z*z} with numpy-like rounding
// (separate mul/add ops, no fma contraction).
__global__ void pack_kernel(const float* __restrict__ inp,
                            const float* __restrict__ outp,
                            float4* __restrict__ inp4,
                            float4* __restrict__ out4) {
    int i = blockIdx.x * blockDim.x + threadIdx.x;
    if (i >= N_PTS) return;
    float x = inp[i * 3 + 0], y = inp[i * 3 + 1], z = inp[i * 3 + 2];
    float s = __fadd_rn(__fadd_rn(__fmul_rn(x, x), __fmul_rn(y, y)), __fmul_rn(z, z));
    inp4[i] = make_float4(x, y, z, s);
    x = outp[i * 3 + 0]; y = outp[i * 3 + 1]; z = outp[i * 3 + 2];
    s = __fadd_rn(__fadd_rn(__fmul_rn(x, x), __fmul_rn(y, y)), __fmul_rn(z, z));
    out4[i] = make_float4(x, y, z, s);
}

// One thread per row, one block-column per j-chunk. All 64 lanes of a wave
// read the same LDS float4 each iteration -> broadcast, conflict-free.
__global__ void __launch_bounds__(TPB)
count_kernel(const float4* __restrict__ inp4, const float4* __restrict__ out4,
             int* __restrict__ cchunk, float T) {
    int rb  = blockIdx.x / NCHUNK;
    int c   = blockIdx.x % NCHUNK;
    int row = rb * TPB + threadIdx.x;
    __shared__ float4 sb[CHUNK];
    for (int t = threadIdx.x; t < CHUNK; t += TPB) sb[t] = inp4[c * CHUNK + t];
    __syncthreads();
    float4 a = out4[row];
    int cnt = 0;
#pragma unroll 4
    for (int jj = 0; jj < CHUNK; ++jj) {
        float4 b  = sb[jj];
        // dot as BLAS-style fma chain; d2 = (a2+b2) - 2*dot with separate roundings
        float dot = __fmaf_rn(a.z, b.z, __fmaf_rn(a.y, b.y, __fmul_rn(a.x, b.x)));
        float d2  = __fsub_rn(__fadd_rn(a.w, b.w), __fadd_rn(dot, dot));
        cnt += (d2 <= T) ? 1 : 0;
    }
    cchunk[row * NCHUNK + c] = cnt;
}

// Per-row exclusive scan over the 16 chunk counts (in place); totals[row] = sum.
__global__ void scan_rows_kernel(int* __restrict__ cchunk, int* __restrict__ totals) {
    int row = blockIdx.x * blockDim.x + threadIdx.x;
    if (row >= M_ROWS) return;
    int base = 0;
#pragma unroll
    for (int c = 0; c < NCHUNK; ++c) {
        int v = cchunk[row * NCHUNK + c];
        cchunk[row * NCHUNK + c] = base;
        base += v;
    }
    totals[row] = base;
}

// One block of 1024 threads: exclusive scan of 16384 totals -> row_splits[0..M]
__global__ void scan_global_kernel(const int* __restrict__ totals,
                                   int* __restrict__ row_splits) {
    __shared__ int sp[1024];
    int t = threadIdx.x;
    int base = t * 16;
    int vals[16];
    int s = 0;
#pragma unroll
    for (int k = 0; k < 16; ++k) { vals[k] = s; s += totals[base + k]; }
    sp[t] = s;
    __syncthreads();
    for (int off = 1; off < 1024; off <<= 1) {
        int v = (t >= off) ? sp[t - off] : 0;
        __syncthreads();
        sp[t] += v;
        __syncthreads();
    }
    int excl = (t == 0) ? 0 : sp[t - 1];
#pragma unroll
    for (int k = 0; k < 16; ++k) row_splits[base + k] = excl + vals[k];
    if (t == 1023) row_splits[16384] = sp[1023];
}

__global__ void fill_kernel(int4* __restrict__ out4) {
    int i = blockIdx.x * blockDim.x + threadIdx.x;
    out4[i] = make_int4(-1, -1, -1, -1);
}

// Re-evaluate predicate; each thread writes its row's hits in ascending-j order
// at row_splits[row] + chunk_prefix, giving the exact nonzero() packing.
__global__ void __launch_bounds__(TPB)
write_kernel(const float4* __restrict__ inp4, const float4* __restrict__ out4,
             const int* __restrict__ cpfx, const int* __restrict__ row_splits,
             int* __restrict__ out_idx, float T) {
    int rb  = blockIdx.x / NCHUNK;
    int c   = blockIdx.x % NCHUNK;
    int row = rb * TPB + threadIdx.x;
    __shared__ float4 sb[CHUNK];
    for (int t = threadIdx.x; t < CHUNK; t += TPB) sb[t] = inp4[c * CHUNK + t];
    __syncthreads();
    float4 a = out4[row];
    int cur = row_splits[row] + cpfx[row * NCHUNK + c];
    int jbase = c * CHUNK;
    for (int jj = 0; jj < CHUNK; ++jj) {
        float4 b  = sb[jj];
        float dot = __fmaf_rn(a.z, b.z, __fmaf_rn(a.y, b.y, __fmul_rn(a.x, b.x)));
        float d2  = __fsub_rn(__fadd_rn(a.w, b.w), __fadd_rn(dot, dot));
        if (d2 <= T) out_idx[cur++] = jbase + jj;
    }
}

extern "C" void kernel_launch(void* const* d_in, const int* in_sizes, int n_in,
                              void* d_out, int out_size, void* d_ws, size_t ws_size,
                              hipStream_t stream) {
    const float* inp  = (const float*)d_in[0];   // inp_positions [16384,3]
    const float* outp = (const float*)d_in[1];   // out_positions [16384,3]
    int* out_idx    = (int*)d_out;               // [MAX_EDGES]
    int* row_splits = out_idx + MAX_EDGES;       // [M+1]

    char* ws = (char*)d_ws;
    float4* inp4 = (float4*)ws;                              // 256 KB
    float4* out4 = (float4*)(ws + 256 * 1024);               // 256 KB
    int* cchunk  = (int*)(ws + 512 * 1024);                  // 1 MB
    int* totals  = (int*)(ws + 512 * 1024 + 1024 * 1024);    // 64 KB

    // T = largest fp32 strictly below (0.1f + 2^-28)^2.
    // d2 <= T  <=>  sqrtf_rn(max(d2,0)) <= 0.1f  (0.1f has odd mantissa, ties round up/away)
    double m  = (double)0.1f + ldexp(1.0, -28);
    double m2 = m * m;
    float  T  = (float)m2;
    if ((double)T >= m2) T = nextafterf(T, 0.0f);

    pack_kernel<<<dim3(N_PTS / TPB), dim3(TPB), 0, stream>>>(inp, outp, inp4, out4);
    count_kernel<<<dim3(ROWBLOCKS * NCHUNK), dim3(TPB), 0, stream>>>(inp4, out4, cchunk, T);
    scan_rows_kernel<<<dim3(ROWBLOCKS), dim3(TPB), 0, stream>>>(cchunk, totals);
    scan_global_kernel<<<dim3(1), dim3(1024), 0, stream>>>(totals, row_splits);
    fill_kernel<<<dim3(MAX_EDGES / 4 / TPB), dim3(TPB), 0, stream>>>((int4*)out_idx);
    write_kernel<<<dim3(ROWBLOCKS * NCHUNK), dim3(TPB), 0, stream>>>(inp4, out4, cchunk, row_splits, out_idx, T);
}

// Round 2
// 84.179 us; speedup vs baseline: 2.0065x; 2.0065x over previous
//
#include <hip/hip_runtime.h>
#include <math.h>

// Problem constants (fixed by the reference)
constexpr int M_ROWS    = 16384;
constexpr int N_PTS     = 16384;
constexpr int MAX_EDGES = 4194304;

constexpr int TPB    = 256;
constexpr int RPT    = 4;                    // rows per thread in pair-eval kernels
constexpr int NCHUNK = 64;                   // j-chunks
constexpr int CHUNK  = N_PTS / NCHUNK;       // 256 j's per chunk
constexpr int WPC    = CHUNK / 32;           // 8 mask words per chunk
constexpr int ROWS_PER_BLOCK = TPB * RPT;    // 1024
constexpr int RB     = M_ROWS / ROWS_PER_BLOCK; // 16

// Pack positions:
//   aq[i] = {x, y, z,  x^2+y^2+z^2}        (query/out_positions)
//   bq[i] = {-2x,-2y,-2z, x^2+y^2+z^2}     (inp_positions, pre-scaled)
// so d2 = fma(ax,bqx, fma(ay,bqy, fma(az,bqz, aw+bqw))) ~= a2+b2-2*dot
__global__ void pack_kernel(const float* __restrict__ inp,
                            const float* __restrict__ outp,
                            float4* __restrict__ bq,
                            float4* __restrict__ aq) {
    int i = blockIdx.x * blockDim.x + threadIdx.x;
    if (i >= N_PTS) return;
    float x = outp[i * 3 + 0], y = outp[i * 3 + 1], z = outp[i * 3 + 2];
    float s = __fadd_rn(__fadd_rn(__fmul_rn(x, x), __fmul_rn(y, y)), __fmul_rn(z, z));
    aq[i] = make_float4(x, y, z, s);
    x = inp[i * 3 + 0]; y = inp[i * 3 + 1]; z = inp[i * 3 + 2];
    s = __fadd_rn(__fadd_rn(__fmul_rn(x, x), __fmul_rn(y, y)), __fmul_rn(z, z));
    bq[i] = make_float4(-2.0f * x, -2.0f * y, -2.0f * z, s);
}

// Pass 1: per-(row, chunk) bitmask (word-major: mask[word*M_ROWS + row]) + counts.
// 4 rows/thread amortize the broadcast LDS read; 32-bit unroll gives
// compile-time bit positions (v_lshl_or with const shift).
template <bool STORE_MASK>
__global__ void __launch_bounds__(TPB)
mask_count_kernel(const float4* __restrict__ aq, const float4* __restrict__ bq,
                  unsigned* __restrict__ mask, int* __restrict__ cchunk, float T) {
    int rb = blockIdx.x / NCHUNK;
    int c  = blockIdx.x % NCHUNK;
    __shared__ float4 sb[CHUNK];
    for (int t = threadIdx.x; t < CHUNK; t += TPB) sb[t] = bq[c * CHUNK + t];
    __syncthreads();
    int row0 = rb * ROWS_PER_BLOCK + threadIdx.x;
    float4 a[RPT];
#pragma unroll
    for (int r = 0; r < RPT; ++r) a[r] = aq[row0 + r * TPB];
    int cnt[RPT] = {0, 0, 0, 0};
    for (int w = 0; w < WPC; ++w) {
        unsigned m[RPT] = {0, 0, 0, 0};
#pragma unroll
        for (int b = 0; b < 32; ++b) {
            float4 q = sb[w * 32 + b];
#pragma unroll
            for (int r = 0; r < RPT; ++r) {
                float d2 = __fmaf_rn(a[r].x, q.x,
                           __fmaf_rn(a[r].y, q.y,
                           __fmaf_rn(a[r].z, q.z, __fadd_rn(a[r].w, q.w))));
                if (d2 <= T) m[r] |= (1u << b);
            }
        }
#pragma unroll
        for (int r = 0; r < RPT; ++r) {
            if (STORE_MASK) mask[(c * WPC + w) * M_ROWS + row0 + r * TPB] = m[r];
            cnt[r] += __popc(m[r]);
        }
    }
#pragma unroll
    for (int r = 0; r < RPT; ++r) cchunk[c * M_ROWS + row0 + r * TPB] = cnt[r];
}

// Per-row exclusive scan over the NCHUNK chunk counts (in place, transposed
// layout so lanes stay coalesced); totals[row] = row sum.
__global__ void scan_rows_kernel(int* __restrict__ cchunk, int* __restrict__ totals) {
    int row = blockIdx.x * blockDim.x + threadIdx.x;
    if (row >= M_ROWS) return;
    int base = 0;
    for (int c = 0; c < NCHUNK; ++c) {
        int v = cchunk[c * M_ROWS + row];
        cchunk[c * M_ROWS + row] = base;
        base += v;
    }
    totals[row] = base;
}

// One block of 1024 threads: exclusive scan of 16384 totals -> row_splits[0..M]
__global__ void scan_global_kernel(const int* __restrict__ totals,
                                   int* __restrict__ row_splits) {
    __shared__ int sp[1024];
    int t = threadIdx.x;
    int base = t * 16;
    int vals[16];
    int s = 0;
#pragma unroll
    for (int k = 0; k < 16; ++k) { vals[k] = s; s += totals[base + k]; }
    sp[t] = s;
    __syncthreads();
    for (int off = 1; off < 1024; off <<= 1) {
        int v = (t >= off) ? sp[t - off] : 0;
        __syncthreads();
        sp[t] += v;
        __syncthreads();
    }
    int excl = (t == 0) ? 0 : sp[t - 1];
#pragma unroll
    for (int k = 0; k < 16; ++k) row_splits[base + k] = excl + vals[k];
    if (t == 1023) row_splits[16384] = sp[1023];
}

__global__ void fill_kernel(int4* __restrict__ out4) {
    int i = blockIdx.x * blockDim.x + threadIdx.x;
    out4[i] = make_int4(-1, -1, -1, -1);
}

// Emit from stored bitmask: thread per (row, chunk); ascending-j bit walk
// reproduces nonzero() packing. ~2 hits per thread on average.
__global__ void __launch_bounds__(TPB)
emit_mask_kernel(const unsigned* __restrict__ mask, const int* __restrict__ cpfx,
                 const int* __restrict__ rs, int* __restrict__ out_idx) {
    int rb  = blockIdx.x / NCHUNK;
    int c   = blockIdx.x % NCHUNK;
    int row = rb * TPB + threadIdx.x;
    int cur = rs[row] + cpfx[c * M_ROWS + row];
    int jbase = c * CHUNK;
#pragma unroll
    for (int w = 0; w < WPC; ++w) {
        unsigned m = mask[(c * WPC + w) * M_ROWS + row];
        while (m) {
            int b = __ffs(m) - 1;
            out_idx[cur++] = jbase + w * 32 + b;
            m &= m - 1;
        }
    }
}

// Fallback emit when ws is too small for the mask: recompute predicate.
__global__ void __launch_bounds__(TPB)
emit_recompute_kernel(const float4* __restrict__ aq, const float4* __restrict__ bq,
                      const int* __restrict__ cpfx, const int* __restrict__ rs,
                      int* __restrict__ out_idx, float T) {
    int rb = blockIdx.x / NCHUNK;
    int c  = blockIdx.x % NCHUNK;
    __shared__ float4 sb[CHUNK];
    for (int t = threadIdx.x; t < CHUNK; t += TPB) sb[t] = bq[c * CHUNK + t];
    __syncthreads();
    int row0 = rb * ROWS_PER_BLOCK + threadIdx.x;
    float4 a[RPT];
    int cur[RPT];
#pragma unroll
    for (int r = 0; r < RPT; ++r) {
        a[r]   = aq[row0 + r * TPB];
        cur[r] = rs[row0 + r * TPB] + cpfx[c * M_ROWS + row0 + r * TPB];
    }
    int jbase = c * CHUNK;
    for (int jj = 0; jj < CHUNK; ++jj) {
        float4 q = sb[jj];
#pragma unroll
        for (int r = 0; r < RPT; ++r) {
            float d2 = __fmaf_rn(a[r].x, q.x,
                       __fmaf_rn(a[r].y, q.y,
                       __fmaf_rn(a[r].z, q.z, __fadd_rn(a[r].w, q.w))));
            if (d2 <= T) out_idx[cur[r]++] = jbase + jj;
        }
    }
}

extern "C" void kernel_launch(void* const* d_in, const int* in_sizes, int n_in,
                              void* d_out, int out_size, void* d_ws, size_t ws_size,
                              hipStream_t stream) {
    const float* inp  = (const float*)d_in[0];   // inp_positions [16384,3]
    const float* outp = (const float*)d_in[1];   // out_positions [16384,3]
    int* out_idx    = (int*)d_out;               // [MAX_EDGES]
    int* row_splits = out_idx + MAX_EDGES;       // [M+1]

    char* ws = (char*)d_ws;
    size_t off = 0;
    float4* bq = (float4*)(ws + off); off += (size_t)N_PTS * 16;          // 256 KB
    float4* aq = (float4*)(ws + off); off += (size_t)M_ROWS * 16;         // 256 KB
    int* cchunk = (int*)(ws + off);   off += (size_t)M_ROWS * NCHUNK * 4; // 4 MB
    int* totals = (int*)(ws + off);   off += (size_t)M_ROWS * 4;          // 64 KB
    unsigned* mask = (unsigned*)(ws + off);
    size_t mask_bytes = (size_t)M_ROWS * (N_PTS / 32) * 4;                // 32 MB
    bool use_mask = (off + mask_bytes) <= ws_size;

    // T = largest fp32 strictly below (0.1f + 2^-28)^2: d2<=T  <=>  sqrt(max(d2,0))<=0.1f
    double m  = (double)0.1f + ldexp(1.0, -28);
    double m2 = m * m;
    float  T  = (float)m2;
    if ((double)T >= m2) T = nextafterf(T, 0.0f);

    pack_kernel<<<dim3(N_PTS / TPB), dim3(TPB), 0, stream>>>(inp, outp, bq, aq);
    if (use_mask)
        mask_count_kernel<true><<<dim3(RB * NCHUNK), dim3(TPB), 0, stream>>>(aq, bq, mask, cchunk, T);
    else
        mask_count_kernel<false><<<dim3(RB * NCHUNK), dim3(TPB), 0, stream>>>(aq, bq, mask, cchunk, T);
    scan_rows_kernel<<<dim3(M_ROWS / TPB), dim3(TPB), 0, stream>>>(cchunk, totals);
    scan_global_kernel<<<dim3(1), dim3(1024), 0, stream>>>(totals, row_splits);
    fill_kernel<<<dim3(MAX_EDGES / 4 / TPB), dim3(TPB), 0, stream>>>((int4*)out_idx);
    if (use_mask)
        emit_mask_kernel<<<dim3((M_ROWS / TPB) * NCHUNK), dim3(TPB), 0, stream>>>(mask, cchunk, row_splits, out_idx);
    else
        emit_recompute_kernel<<<dim3(RB * NCHUNK), dim3(TPB), 0, stream>>>(aq, bq, cchunk, row_splits, out_idx, T);
}

// Round 3
// 79.424 us; speedup vs baseline: 2.1266x; 1.0599x over previous
//
#include <hip/hip_runtime.h>
#include <math.h>

typedef float f32x2 __attribute__((ext_vector_type(2)));

// Problem constants (fixed by the reference)
constexpr int M_ROWS    = 16384;
constexpr int N_PTS     = 16384;
constexpr int MAX_EDGES = 4194304;

constexpr int TPB    = 256;
constexpr int RPT    = 8;                        // rows per thread
constexpr int NPAIR  = RPT / 2;                  // packed row-pairs per thread
constexpr int NCHUNK = 256;                      // j-chunks
constexpr int CHUNK  = N_PTS / NCHUNK;           // 64 j per chunk
constexpr int WPC    = CHUNK / 32;               // 2 mask words per chunk
constexpr int ROWS_PER_BLOCK = TPB * RPT;        // 2048
constexpr int RB     = M_ROWS / ROWS_PER_BLOCK;  // 8
constexpr int CGRP   = 16;                       // chunks per coarse prefix group
constexpr int NGRP   = NCHUNK / CGRP;            // 16

static __device__ __forceinline__ f32x2 pk_fma(f32x2 a, f32x2 b, f32x2 c) {
#if __has_builtin(__builtin_elementwise_fma)
    return __builtin_elementwise_fma(a, b, c);   // -> v_pk_fma_f32 on gfx90a+
#else
    f32x2 r; r.x = __fmaf_rn(a.x, b.x, c.x); r.y = __fmaf_rn(a.y, b.y, c.y); return r;
#endif
}

// m = (m << 1) | (t <= tr), via v_cmp + v_addc (2 VALU).
static __device__ __forceinline__ void bitstep(unsigned& m, float t, float tr) {
    asm("v_cmp_le_f32 vcc, %1, %2\n\t"
        "v_addc_co_u32 %0, vcc, %0, %0, vcc"
        : "+v"(m) : "v"(t), "v"(tr) : "vcc");
}

// Pass 1 (pack fused): per-(row, chunk) bitmask + u8 counts.
// Predicate: fma(ax,-2qx, fma(ay,-2qy, fma(az,-2qz, |q|^2))) <= T - |a|^2
// Rows processed as packed pairs (v_pk_fma_f32); bits accumulated MSB-first
// (b descending) so bit b corresponds to j-offset b.
__global__ void __launch_bounds__(TPB)
mask_count_kernel(const float* __restrict__ inp, const float* __restrict__ outp,
                  unsigned* __restrict__ mask, unsigned char* __restrict__ cchunk,
                  float T) {
    int rb = blockIdx.x / NCHUNK;
    int c  = blockIdx.x % NCHUNK;
    int t  = threadIdx.x;
    __shared__ f32x2 sb[CHUNK * 4];              // {x2,y2,z2,w2} per point, duplicated
    if (t < CHUNK) {
        int j = c * CHUNK + t;
        float x = inp[j * 3 + 0], y = inp[j * 3 + 1], z = inp[j * 3 + 2];
        float s = __fadd_rn(__fadd_rn(__fmul_rn(x, x), __fmul_rn(y, y)), __fmul_rn(z, z));
        float nx = -2.0f * x, ny = -2.0f * y, nz = -2.0f * z;
        sb[t * 4 + 0] = (f32x2){nx, nx};
        sb[t * 4 + 1] = (f32x2){ny, ny};
        sb[t * 4 + 2] = (f32x2){nz, nz};
        sb[t * 4 + 3] = (f32x2){s, s};
    }
    __syncthreads();
    int row0 = rb * ROWS_PER_BLOCK + t;
    f32x2 ax[NPAIR], ay[NPAIR], az[NPAIR], Tr[NPAIR];
#pragma unroll
    for (int k = 0; k < NPAIR; ++k) {
        int r0 = row0 + (2 * k) * TPB;
        int r1 = row0 + (2 * k + 1) * TPB;
        float x0 = outp[r0 * 3 + 0], y0 = outp[r0 * 3 + 1], z0 = outp[r0 * 3 + 2];
        float x1 = outp[r1 * 3 + 0], y1 = outp[r1 * 3 + 1], z1 = outp[r1 * 3 + 2];
        float w0 = __fadd_rn(__fadd_rn(__fmul_rn(x0, x0), __fmul_rn(y0, y0)), __fmul_rn(z0, z0));
        float w1 = __fadd_rn(__fadd_rn(__fmul_rn(x1, x1), __fmul_rn(y1, y1)), __fmul_rn(z1, z1));
        ax[k] = (f32x2){x0, x1};
        ay[k] = (f32x2){y0, y1};
        az[k] = (f32x2){z0, z1};
        Tr[k] = (f32x2){__fsub_rn(T, w0), __fsub_rn(T, w1)};
    }
    int cnt[RPT];
#pragma unroll
    for (int r = 0; r < RPT; ++r) cnt[r] = 0;
#pragma unroll
    for (int w = 0; w < WPC; ++w) {
        unsigned m[RPT];
#pragma unroll
        for (int r = 0; r < RPT; ++r) m[r] = 0u;
#pragma unroll
        for (int b = 31; b >= 0; --b) {
            int jj = w * 32 + b;
            f32x2 qx = sb[jj * 4 + 0], qy = sb[jj * 4 + 1];
            f32x2 qz = sb[jj * 4 + 2], qw = sb[jj * 4 + 3];
#pragma unroll
            for (int k = 0; k < NPAIR; ++k) {
                f32x2 acc = pk_fma(az[k], qz, qw);
                acc = pk_fma(ay[k], qy, acc);
                acc = pk_fma(ax[k], qx, acc);
                bitstep(m[2 * k + 0], acc.x, Tr[k].x);
                bitstep(m[2 * k + 1], acc.y, Tr[k].y);
            }
        }
#pragma unroll
        for (int r = 0; r < RPT; ++r) {
            mask[(size_t)(c * WPC + w) * M_ROWS + row0 + r * TPB] = m[r];
            cnt[r] += __popc(m[r]);
        }
    }
#pragma unroll
    for (int r = 0; r < RPT; ++r)
        cchunk[(size_t)c * M_ROWS + row0 + r * TPB] = (unsigned char)cnt[r];
}

// Per-row scan over 256 u8 chunk counts, LDS-tiled so global loads stay
// coalesced and bulk-issued. Emits coarse u16 prefixes every CGRP chunks
// plus per-row totals.
__global__ void __launch_bounds__(256)
scan_rows_kernel(const unsigned* __restrict__ cc32, unsigned short* __restrict__ cpfxc,
                 int* __restrict__ totals) {
    __shared__ unsigned tile[64][64];            // [c_local][uint over 4 rows]
    int row0 = blockIdx.x * 256;
    int t = threadIdx.x;
    int sum = 0;
    for (int c0 = 0; c0 < NCHUNK; c0 += 64) {
        __syncthreads();
        for (int i = t; i < 64 * 64; i += 256) {
            int cl = i >> 6, rw = i & 63;
            tile[cl][rw] = cc32[(size_t)(c0 + cl) * (M_ROWS / 4) + (row0 / 4) + rw];
        }
        __syncthreads();
#pragma unroll 16
        for (int cl = 0; cl < 64; ++cl) {
            int c = c0 + cl;
            if ((c & (CGRP - 1)) == 0)
                cpfxc[(size_t)(c / CGRP) * M_ROWS + row0 + t] = (unsigned short)sum;
            unsigned wv = tile[cl][t >> 2];
            sum += (wv >> ((t & 3) * 8)) & 0xffu;
        }
    }
    totals[row0 + t] = sum;
}

// One block: exclusive scan of 16384 totals -> row_splits[0..16384]
__global__ void __launch_bounds__(1024)
scan_global_kernel(const int* __restrict__ totals, int* __restrict__ row_splits) {
    __shared__ int sp[1024];
    int t = threadIdx.x;
    const int4* t4 = (const int4*)totals;
    int4 v0 = t4[t * 4 + 0], v1 = t4[t * 4 + 1], v2 = t4[t * 4 + 2], v3 = t4[t * 4 + 3];
    int vals[16] = {v0.x, v0.y, v0.z, v0.w, v1.x, v1.y, v1.z, v1.w,
                    v2.x, v2.y, v2.z, v2.w, v3.x, v3.y, v3.z, v3.w};
    int pre[16];
    int s = 0;
#pragma unroll
    for (int k = 0; k < 16; ++k) { pre[k] = s; s += vals[k]; }
    sp[t] = s;
    __syncthreads();
    for (int off = 1; off < 1024; off <<= 1) {
        int v = (t >= off) ? sp[t - off] : 0;
        __syncthreads();
        sp[t] += v;
        __syncthreads();
    }
    int excl = (t == 0) ? 0 : sp[t - 1];
#pragma unroll
    for (int k = 0; k < 16; ++k) row_splits[t * 16 + k] = excl + pre[k];
    if (t == 1023) row_splits[16384] = sp[1023];
}

__global__ void fill_kernel(int4* __restrict__ out4) {
    int i = blockIdx.x * blockDim.x + threadIdx.x;
    out4[i] = make_int4(-1, -1, -1, -1);
}

// Emit: block per (row-block, chunk-group); thread walks its row's 16 chunks
// (32 mask words) ascending, writing hit j's packed from the coarse prefix.
__global__ void __launch_bounds__(TPB)
emit_mask_kernel(const unsigned* __restrict__ mask, const unsigned short* __restrict__ cpfxc,
                 const int* __restrict__ rs, int* __restrict__ out_idx) {
    int rb  = blockIdx.x / NGRP;
    int cg  = blockIdx.x % NGRP;
    int row = rb * TPB + threadIdx.x;
    int cur = rs[row] + (int)cpfxc[(size_t)cg * M_ROWS + row];
#pragma unroll 4
    for (int c = cg * CGRP; c < (cg + 1) * CGRP; ++c) {
#pragma unroll
        for (int w = 0; w < WPC; ++w) {
            unsigned m = mask[(size_t)(c * WPC + w) * M_ROWS + row];
            int jb = c * CHUNK + w * 32;
            while (m) {
                int b = __ffs(m) - 1;
                out_idx[cur++] = jb + b;
                m &= m - 1;
            }
        }
    }
}

extern "C" void kernel_launch(void* const* d_in, const int* in_sizes, int n_in,
                              void* d_out, int out_size, void* d_ws, size_t ws_size,
                              hipStream_t stream) {
    const float* inp  = (const float*)d_in[0];   // inp_positions [16384,3]
    const float* outp = (const float*)d_in[1];   // out_positions [16384,3]
    int* out_idx    = (int*)d_out;               // [MAX_EDGES]
    int* row_splits = out_idx + MAX_EDGES;       // [M+1]

    char* ws = (char*)d_ws;
    size_t off = 0;
    unsigned* mask = (unsigned*)(ws + off);      // 32 MB
    off += (size_t)M_ROWS * (N_PTS / 32) * 4;
    unsigned char* cchunk = (unsigned char*)(ws + off);   // 4 MB
    off += (size_t)M_ROWS * NCHUNK;
    unsigned short* cpfxc = (unsigned short*)(ws + off);  // 512 KB
    off += (size_t)M_ROWS * NGRP * 2;
    int* totals = (int*)(ws + off);                       // 64 KB
    off += (size_t)M_ROWS * 4;
    if (off > ws_size) return;  // proven to fit in prior rounds (<= 36.8 MB)

    // T = largest fp32 strictly below (0.1f + 2^-28)^2: d2<=T <=> sqrt(max(d2,0))<=0.1f
    double md  = (double)0.1f + ldexp(1.0, -28);
    double m2 = md * md;
    float  T  = (float)m2;
    if ((double)T >= m2) T = nextafterf(T, 0.0f);

    mask_count_kernel<<<dim3(RB * NCHUNK), dim3(TPB), 0, stream>>>(inp, outp, mask, cchunk, T);
    scan_rows_kernel<<<dim3(M_ROWS / 256), dim3(256), 0, stream>>>((const unsigned*)cchunk, cpfxc, totals);
    scan_global_kernel<<<dim3(1), dim3(1024), 0, stream>>>(totals, row_splits);
    fill_kernel<<<dim3(MAX_EDGES / 4 / TPB), dim3(TPB), 0, stream>>>((int4*)out_idx);
    emit_mask_kernel<<<dim3((M_ROWS / TPB) * NGRP), dim3(TPB), 0, stream>>>(mask, cpfxc, row_splits, out_idx);
}